// Round 10
// baseline (1277.766 us; speedup 1.0000x reference)
//
#include <hip/hip_runtime.h>
#include <cstddef>

#define NN 100000
#define NE 1600000
#define NBLK 98   // ceil(NN / 1024)

// ===========================================================================
// CSR build: histogram(dst) -> hierarchical exclusive scan -> scatter
// ===========================================================================
__global__ __launch_bounds__(256) void hist_dst(const int* __restrict__ ei,
                                                int* __restrict__ deg)
{
    int i = blockIdx.x * 256 + threadIdx.x;
    int stride = gridDim.x * 256;
    for (int e = i; e < NE; e += stride)
        atomicAdd(&deg[ei[NE + e]], 1);
}

__global__ __launch_bounds__(1024) void deg_block_sum(const int* __restrict__ deg,
                                                      int* __restrict__ bsum)
{
    __shared__ int s[16];
    int t = threadIdx.x;
    int i = blockIdx.x * 1024 + t;
    int v = (i < NN) ? deg[i] : 0;
    #pragma unroll
    for (int o = 32; o > 0; o >>= 1) v += __shfl_down(v, o, 64);
    if ((t & 63) == 0) s[t >> 6] = v;
    __syncthreads();
    if (t < 64) {
        int w = (t < 16) ? s[t] : 0;
        #pragma unroll
        for (int o = 8; o > 0; o >>= 1) w += __shfl_down(w, o, 64);
        if (t == 0) bsum[blockIdx.x] = w;
    }
}

__global__ __launch_bounds__(128) void scan_bsum(int* __restrict__ bsum,
                                                 int* __restrict__ off)
{
    __shared__ int s[128];
    int t = threadIdx.x;
    int v = (t < NBLK) ? bsum[t] : 0;
    s[t] = v;
    __syncthreads();
    #pragma unroll
    for (int o = 1; o < 128; o <<= 1) {
        int u = (t >= o) ? s[t - o] : 0;
        __syncthreads();
        s[t] += u;
        __syncthreads();
    }
    if (t < NBLK) bsum[t] = s[t] - v;   // exclusive block offset
    if (t == 127) off[NN] = s[127];     // grand total
}

__global__ __launch_bounds__(1024) void deg_block_scan(int* __restrict__ deg,
                                                       int* __restrict__ off,
                                                       const int* __restrict__ bsum)
{
    __shared__ int s[1024];
    int t = threadIdx.x;
    int i = blockIdx.x * 1024 + t;
    int v = (i < NN) ? deg[i] : 0;
    s[t] = v;
    __syncthreads();
    #pragma unroll
    for (int o = 1; o < 1024; o <<= 1) {
        int u = (t >= o) ? s[t - o] : 0;
        __syncthreads();
        s[t] += u;
        __syncthreads();
    }
    int excl = s[t] - v + bsum[blockIdx.x];
    if (i < NN) { off[i] = excl; deg[i] = excl; }
}

__global__ __launch_bounds__(256) void scatter_perm(const int* __restrict__ ei,
                                                    int* __restrict__ cur,
                                                    int2* __restrict__ perm2)
{
    int i = blockIdx.x * 256 + threadIdx.x;
    int stride = gridDim.x * 256;
    for (int e = i; e < NE; e += stride) {
        int s = ei[e];
        int d = ei[NE + e];
        int pos = atomicAdd(&cur[d], 1);
        perm2[pos] = make_int2(e, s);
    }
}

// ===========================================================================
// conv1 gather: one FULL wave per node, 2 channels/lane (128 ch).
// Attr broadcast on the LDS PIPE via ds_bpermute with constant-folded
// offset:imm (base = laundered zero VGPR). R9 showed the 16 v_readlane
// broadcasts/edge are the VALU bottleneck (~280 busy-cyc/edge vs ~112
// hand-counted => readlane ~8cyc each). ds_bpermute runs on the (idle) LDS
// pipe CONCURRENTLY with the FMA stream, and the folded offsets cost zero
// VALU ops. VALU/edge drops to ~38 insts (32 FMA + misc).
//  - records: one coalesced vector load per 64 edges (perm2[base+lane])
//  - attrs: cooperative quad load (lane q*16+k holds attr k of edge q)
//  - x rows: per-lane float2, src row via SGPR readlane (scalar addressing)
// aggr1[n] = sum_{e: dst=n} relu(x[src_e] + ea[e] @ We1 + be1)
// ===========================================================================
__global__ __launch_bounds__(256, 4) void conv1_gather(
    const float* __restrict__ x, const float* __restrict__ ea,
    const float* __restrict__ We, const float* __restrict__ be,
    const int* __restrict__ off, const int2* __restrict__ perm2,
    float* __restrict__ aggr)
{
    int t = threadIdx.x;
    int lane = t & 63;
    int n = blockIdx.x * 4 + (t >> 6);
    if (n >= NN) return;

    const float2* W2 = (const float2*)We;
    float2 rw[16];
    #pragma unroll
    for (int k = 0; k < 16; k++) rw[k] = W2[(k << 6) + lane];
    float2 bias = ((const float2*)be)[lane];

    int qsel = lane >> 4;        // which edge of a quad this lane loads
    int ksel = lane & 15;        // which attr within that edge

    // laundered zero: forces a VGPR base so each bpermute index folds into
    // the instruction's offset:imm (no per-broadcast VALU address math)
    int zr = 0;
    asm("" : "+v"(zr));

    const int* eai = (const int*)ea;

    int j0 = off[n], j1 = off[n + 1];
    float2 acc = make_float2(0.f, 0.f);

    for (int base = j0; base < j1; base += 64) {
        int cnt = min(64, j1 - base);
        int2 rec = perm2[min(base + lane, j1 - 1)];   // coalesced coop load
        int nq = (cnt + 3) >> 2;

        auto loadAttr = [&](int q) -> int {
            int ei = min(q * 4 + qsel, cnt - 1);
            int e  = __shfl(rec.x, ei);               // 1 bpermute / quad
            return eai[(size_t)(unsigned)e * 16 + ksel];
        };
        auto loadX = [&](int q, float2* xv) {
            #pragma unroll
            for (int sub = 0; sub < 4; sub++) {
                int ei = min(q * 4 + sub, cnt - 1);   // uniform
                int s  = __builtin_amdgcn_readlane(rec.y, ei);
                xv[sub] = *(const float2*)(x + (size_t)(unsigned)s * 128 + (lane << 1));
            }
        };
        auto computeQ = [&](int q, int av, const float2* xv) {
            #pragma unroll
            for (int sub = 0; sub < 4; sub++) {
                if (q * 4 + sub >= cnt) break;        // wave-uniform guard
                float2 m = bias;
                #pragma unroll
                for (int k = 0; k < 16; k++) {
                    // value for (sub,k) lives in lane sub*16+k
                    float a = __int_as_float(
                        __builtin_amdgcn_ds_bpermute(zr + (sub << 6) + (k << 2), av));
                    m.x = fmaf(a, rw[k].x, m.x);
                    m.y = fmaf(a, rw[k].y, m.y);
                }
                acc.x += fmaxf(xv[sub].x + m.x, 0.f);
                acc.y += fmaxf(xv[sub].y + m.y, 0.f);
            }
        };

        // prologue: quad 0 in flight
        int avA = loadAttr(0);
        float2 xA[4]; loadX(0, xA);

        for (int q = 0; q < nq; q += 2) {
            // issue quad q+1 (set B), then compute quad q (set A)
            int avB = loadAttr(q + 1);
            float2 xB[4]; loadX(q + 1, xB);
            computeQ(q, avA, xA);
            // issue quad q+2 (set A), then compute quad q+1 (set B)
            avA = loadAttr(q + 2);
            loadX(q + 2, xA);
            if (q + 1 < nq) computeQ(q + 1, avB, xB);
        }
    }
    *(float2*)(aggr + (size_t)n * 128 + (lane << 1)) = acc;
}

// ===========================================================================
// conv_mu + conv_logstd gather, fused: one FULL wave per node. Trees split
// across the wave: lanes 0-31 = mu (W2), lanes 32-63 = logstd (W3),
// 2 channels/lane. Attr broadcasts shared between trees (one bpermute
// serves all 64 lanes). Same LDS-pipe broadcast as conv1_gather.
// ===========================================================================
__global__ __launch_bounds__(256, 4) void conv23_gather(
    const float* __restrict__ h, const float* __restrict__ ea,
    const float* __restrict__ We2, const float* __restrict__ be2,
    const float* __restrict__ We3, const float* __restrict__ be3,
    const int* __restrict__ off, const int2* __restrict__ perm2,
    float* __restrict__ aggr2, float* __restrict__ aggr3)
{
    int t = threadIdx.x;
    int lane = t & 63;
    int half = lane >> 5;            // 0 = mu tree, 1 = logstd tree
    int cl = lane & 31;
    int co = cl << 1;                // channel pair within the tree
    int n = blockIdx.x * 4 + (t >> 6);
    if (n >= NN) return;

    const float2* Wp = (const float2*)(half ? We3 : We2);
    const float2* bp = (const float2*)(half ? be3 : be2);
    float2 rw[16];
    #pragma unroll
    for (int k = 0; k < 16; k++) rw[k] = Wp[(k << 5) + cl];
    float2 bias = bp[cl];

    int qsel = lane >> 4;
    int ksel = lane & 15;

    int zr = 0;
    asm("" : "+v"(zr));

    const int* eai = (const int*)ea;

    int j0 = off[n], j1 = off[n + 1];
    float2 acc = make_float2(0.f, 0.f);

    for (int base = j0; base < j1; base += 64) {
        int cnt = min(64, j1 - base);
        int2 rec = perm2[min(base + lane, j1 - 1)];
        int nq = (cnt + 3) >> 2;

        auto loadAttr = [&](int q) -> int {
            int ei = min(q * 4 + qsel, cnt - 1);
            int e  = __shfl(rec.x, ei);
            return eai[(size_t)(unsigned)e * 16 + ksel];
        };
        auto loadH = [&](int q, float2* hv) {
            #pragma unroll
            for (int sub = 0; sub < 4; sub++) {
                int ei = min(q * 4 + sub, cnt - 1);
                int s  = __builtin_amdgcn_readlane(rec.y, ei);
                hv[sub] = *(const float2*)(h + (size_t)(unsigned)s * 64 + co);
            }
        };
        auto computeQ = [&](int q, int av, const float2* hv) {
            #pragma unroll
            for (int sub = 0; sub < 4; sub++) {
                if (q * 4 + sub >= cnt) break;
                float2 m = bias;
                #pragma unroll
                for (int k = 0; k < 16; k++) {
                    float a = __int_as_float(
                        __builtin_amdgcn_ds_bpermute(zr + (sub << 6) + (k << 2), av));
                    m.x = fmaf(a, rw[k].x, m.x);
                    m.y = fmaf(a, rw[k].y, m.y);
                }
                acc.x += fmaxf(hv[sub].x + m.x, 0.f);
                acc.y += fmaxf(hv[sub].y + m.y, 0.f);
            }
        };

        int avA = loadAttr(0);
        float2 hA[4]; loadH(0, hA);

        for (int q = 0; q < nq; q += 2) {
            int avB = loadAttr(q + 1);
            float2 hB[4]; loadH(q + 1, hB);
            computeQ(q, avA, hA);
            avA = loadAttr(q + 2);
            loadH(q + 2, hA);
            if (q + 1 < nq) computeQ(q + 1, avB, hB);
        }
    }
    float* dstp = (half ? aggr3 : aggr2) + (size_t)n * 64 + co;
    *(float2*)dstp = acc;
}

// ===========================================================================
// Node MLP: out = epilogue( relu((xin+aggr) @ Wa + ba) @ Wb + bb )
// KIN -> 64 -> 64. 64 nodes per block, 256 threads, 4x4 register tiles.
// SLIM-LDS: weights/biases read directly from global (L1/L2-resident,
// shared by all blocks). Only the per-node input tile lives in LDS.
// mode: 0 = none, 1 = relu, 2 = clip(-10, 10)
// ===========================================================================
template <int KIN>
__global__ __launch_bounds__(256) void node_mlp(
    const float* __restrict__ xin, const float* __restrict__ aggr,
    const float* __restrict__ Wa, const float* __restrict__ ba,
    const float* __restrict__ Wb, const float* __restrict__ bb,
    float* __restrict__ out, int mode)
{
    constexpr int S0 = KIN + 4;
    constexpr int K4 = KIN / 4;
    __shared__ float sh[64 * S0];
    int t = threadIdx.x;

    int nb = blockIdx.x << 6;
    for (int i = t; i < 64 * K4; i += 256) {
        int n = i / K4, k4 = i % K4;
        int node = nb + n;
        float4 v = make_float4(0.f, 0.f, 0.f, 0.f);
        if (node < NN) {
            float4 a = ((const float4*)(xin  + (size_t)node * KIN))[k4];
            float4 b = ((const float4*)(aggr + (size_t)node * KIN))[k4];
            v = make_float4(a.x + b.x, a.y + b.y, a.z + b.z, a.w + b.w);
        }
        *(float4*)&sh[n * S0 + (k4 << 2)] = v;
    }
    __syncthreads();

    int tx = t & 15, ty = t >> 4;
    int c0 = tx << 2, n0 = ty << 2;

    float4 b1 = *(const float4*)&ba[c0];
    float acc[4][4];
    #pragma unroll
    for (int i = 0; i < 4; i++) { acc[i][0] = b1.x; acc[i][1] = b1.y; acc[i][2] = b1.z; acc[i][3] = b1.w; }
    for (int k4 = 0; k4 < K4; k4++) {
        int k = k4 << 2;
        float4 w0 = *(const float4*)&Wa[((k + 0) << 6) + c0];
        float4 w1 = *(const float4*)&Wa[((k + 1) << 6) + c0];
        float4 w2 = *(const float4*)&Wa[((k + 2) << 6) + c0];
        float4 w3 = *(const float4*)&Wa[((k + 3) << 6) + c0];
        #pragma unroll
        for (int i = 0; i < 4; i++) {
            float4 hv = *(const float4*)&sh[(n0 + i) * S0 + k];
            acc[i][0] = fmaf(hv.x, w0.x, acc[i][0]); acc[i][1] = fmaf(hv.x, w0.y, acc[i][1]);
            acc[i][2] = fmaf(hv.x, w0.z, acc[i][2]); acc[i][3] = fmaf(hv.x, w0.w, acc[i][3]);
            acc[i][0] = fmaf(hv.y, w1.x, acc[i][0]); acc[i][1] = fmaf(hv.y, w1.y, acc[i][1]);
            acc[i][2] = fmaf(hv.y, w1.z, acc[i][2]); acc[i][3] = fmaf(hv.y, w1.w, acc[i][3]);
            acc[i][0] = fmaf(hv.z, w2.x, acc[i][0]); acc[i][1] = fmaf(hv.z, w2.y, acc[i][1]);
            acc[i][2] = fmaf(hv.z, w2.z, acc[i][2]); acc[i][3] = fmaf(hv.z, w2.w, acc[i][3]);
            acc[i][0] = fmaf(hv.w, w3.x, acc[i][0]); acc[i][1] = fmaf(hv.w, w3.y, acc[i][1]);
            acc[i][2] = fmaf(hv.w, w3.z, acc[i][2]); acc[i][3] = fmaf(hv.w, w3.w, acc[i][3]);
        }
    }
    __syncthreads();
    #pragma unroll
    for (int i = 0; i < 4; i++) {
        float4 v = make_float4(fmaxf(acc[i][0], 0.f), fmaxf(acc[i][1], 0.f),
                               fmaxf(acc[i][2], 0.f), fmaxf(acc[i][3], 0.f));
        *(float4*)&sh[(n0 + i) * 68 + c0] = v;
    }
    __syncthreads();

    float4 b2 = *(const float4*)&bb[c0];
    float acc2[4][4];
    #pragma unroll
    for (int i = 0; i < 4; i++) { acc2[i][0] = b2.x; acc2[i][1] = b2.y; acc2[i][2] = b2.z; acc2[i][3] = b2.w; }
    for (int k4 = 0; k4 < 16; k4++) {
        int k = k4 << 2;
        float4 w0 = *(const float4*)&Wb[((k + 0) << 6) + c0];
        float4 w1 = *(const float4*)&Wb[((k + 1) << 6) + c0];
        float4 w2 = *(const float4*)&Wb[((k + 2) << 6) + c0];
        float4 w3 = *(const float4*)&Wb[((k + 3) << 6) + c0];
        #pragma unroll
        for (int i = 0; i < 4; i++) {
            float4 hv = *(const float4*)&sh[(n0 + i) * 68 + k];
            acc2[i][0] = fmaf(hv.x, w0.x, acc2[i][0]); acc2[i][1] = fmaf(hv.x, w0.y, acc2[i][1]);
            acc2[i][2] = fmaf(hv.x, w0.z, acc2[i][2]); acc2[i][3] = fmaf(hv.x, w0.w, acc2[i][3]);
            acc2[i][0] = fmaf(hv.y, w1.x, acc2[i][0]); acc2[i][1] = fmaf(hv.y, w1.y, acc2[i][1]);
            acc2[i][2] = fmaf(hv.y, w1.z, acc2[i][2]); acc2[i][3] = fmaf(hv.y, w1.w, acc2[i][3]);
            acc2[i][0] = fmaf(hv.z, w2.x, acc2[i][0]); acc2[i][1] = fmaf(hv.z, w2.y, acc2[i][1]);
            acc2[i][2] = fmaf(hv.z, w2.z, acc2[i][2]); acc2[i][3] = fmaf(hv.z, w2.w, acc2[i][3]);
            acc2[i][0] = fmaf(hv.w, w3.x, acc2[i][0]); acc2[i][1] = fmaf(hv.w, w3.y, acc2[i][1]);
            acc2[i][2] = fmaf(hv.w, w3.z, acc2[i][2]); acc2[i][3] = fmaf(hv.w, w3.w, acc2[i][3]);
        }
    }

    #pragma unroll
    for (int i = 0; i < 4; i++) {
        int node = nb + n0 + i;
        if (node >= NN) continue;
        float4 v = make_float4(acc2[i][0], acc2[i][1], acc2[i][2], acc2[i][3]);
        if (mode == 1) {
            v = make_float4(fmaxf(v.x, 0.f), fmaxf(v.y, 0.f), fmaxf(v.z, 0.f), fmaxf(v.w, 0.f));
        } else if (mode == 2) {
            v = make_float4(fminf(fmaxf(v.x, -10.f), 10.f), fminf(fmaxf(v.y, -10.f), 10.f),
                            fminf(fmaxf(v.z, -10.f), 10.f), fminf(fmaxf(v.w, -10.f), 10.f));
        }
        *(float4*)(out + (size_t)node * 64 + c0) = v;
    }
}

extern "C" void kernel_launch(void* const* d_in, const int* in_sizes, int n_in,
                              void* d_out, int out_size, void* d_ws, size_t ws_size,
                              hipStream_t stream)
{
    const float* x   = (const float*)d_in[0];
    const int*   ei  = (const int*)  d_in[1];
    const float* ea  = (const float*)d_in[2];
    const float* We1 = (const float*)d_in[3];
    const float* be1 = (const float*)d_in[4];
    const float* W1a = (const float*)d_in[5];
    const float* b1a = (const float*)d_in[6];
    const float* W1b = (const float*)d_in[7];
    const float* b1b = (const float*)d_in[8];
    const float* We2 = (const float*)d_in[9];
    const float* be2 = (const float*)d_in[10];
    const float* W2a = (const float*)d_in[11];
    const float* b2a = (const float*)d_in[12];
    const float* W2b = (const float*)d_in[13];
    const float* b2b = (const float*)d_in[14];
    const float* We3 = (const float*)d_in[15];
    const float* be3 = (const float*)d_in[16];
    const float* W3a = (const float*)d_in[17];
    const float* b3a = (const float*)d_in[18];
    const float* W3b = (const float*)d_in[19];
    const float* b3b = (const float*)d_in[20];

    float* out = (float*)d_out;
    float* ws = (float*)d_ws;
    // float scratch: aggr1 [12.8M] (later aliased by aggr2/aggr3), h [6.4M]
    float* aggr1 = ws;
    float* h     = ws + 12800000;
    float* aggr2 = ws;              // aliases aggr1 (dead after node_mlp<128>)
    float* aggr3 = ws + 6400000;
    // int scratch after 19.2M floats: off [NN+1], cur [NN], perm2 [2*NE]
    int* ibase = (int*)(ws + 19200000);
    int* off   = ibase;
    int* cur   = ibase + (NN + 1);
    int2* perm2 = (int2*)(ibase + (2 * NN + 2));
    // 98 block sums live in the (currently idle) aggr3 float region —
    // CSR build completes before any conv kernel touches aggr3.
    int* bsum  = (int*)(ws + 6400000);

    // ---- CSR build (shared by conv1 and conv23) ----
    hipMemsetAsync(cur, 0, (size_t)NN * sizeof(int), stream);
    hist_dst<<<2048, 256, 0, stream>>>(ei, cur);
    deg_block_sum<<<NBLK, 1024, 0, stream>>>(cur, bsum);
    scan_bsum<<<1, 128, 0, stream>>>(bsum, off);
    deg_block_scan<<<NBLK, 1024, 0, stream>>>(cur, off, bsum); // cur -> cursor
    scatter_perm<<<2048, 256, 0, stream>>>(ei, cur, perm2);

    // ---- layer 1 ----
    conv1_gather<<<(NN + 3) / 4, 256, 0, stream>>>(x, ea, We1, be1, off, perm2, aggr1);
    node_mlp<128><<<(NN + 63) / 64, 256, 0, stream>>>(x, aggr1, W1a, b1a, W1b, b1b, h, 1);

    // ---- layers 2+3 (fused edge pass) ----
    conv23_gather<<<(NN + 3) / 4, 256, 0, stream>>>(h, ea, We2, be2, We3, be3,
                                                    off, perm2, aggr2, aggr3);
    node_mlp<64><<<(NN + 63) / 64, 256, 0, stream>>>(h, aggr2, W2a, b2a, W2b, b2b, out, 0);
    node_mlp<64><<<(NN + 63) / 64, 256, 0, stream>>>(h, aggr3, W3a, b3a, W3b, b3b,
                                                     out + (size_t)NN * 64, 2);
}

// Round 11
// 809.918 us; speedup vs baseline: 1.5776x; 1.5776x over previous
//
#include <hip/hip_runtime.h>
#include <cstddef>

#define NN 100000
#define NE 1600000
#define NBLK 98   // ceil(NN / 1024)

typedef __attribute__((ext_vector_type(8))) short bf16x8;
typedef __attribute__((ext_vector_type(4))) float f32x4;
union ABu { unsigned u[4]; bf16x8 v; };

// RNE-pack two f32 into one u32 of 2 bf16 (lo = a, hi = b)
__device__ __forceinline__ unsigned pkbf16(float a, float b)
{
    unsigned r;
    asm("v_cvt_pk_bf16_f32 %0, %1, %2" : "=v"(r) : "v"(a), "v"(b));
    return r;
}

// ===========================================================================
// CSR build: histogram(dst) -> hierarchical exclusive scan -> scatter
// ===========================================================================
__global__ __launch_bounds__(256) void hist_dst(const int* __restrict__ ei,
                                                int* __restrict__ deg)
{
    int i = blockIdx.x * 256 + threadIdx.x;
    int stride = gridDim.x * 256;
    for (int e = i; e < NE; e += stride)
        atomicAdd(&deg[ei[NE + e]], 1);
}

__global__ __launch_bounds__(1024) void deg_block_sum(const int* __restrict__ deg,
                                                      int* __restrict__ bsum)
{
    __shared__ int s[16];
    int t = threadIdx.x;
    int i = blockIdx.x * 1024 + t;
    int v = (i < NN) ? deg[i] : 0;
    #pragma unroll
    for (int o = 32; o > 0; o >>= 1) v += __shfl_down(v, o, 64);
    if ((t & 63) == 0) s[t >> 6] = v;
    __syncthreads();
    if (t < 64) {
        int w = (t < 16) ? s[t] : 0;
        #pragma unroll
        for (int o = 8; o > 0; o >>= 1) w += __shfl_down(w, o, 64);
        if (t == 0) bsum[blockIdx.x] = w;
    }
}

__global__ __launch_bounds__(128) void scan_bsum(int* __restrict__ bsum,
                                                 int* __restrict__ off)
{
    __shared__ int s[128];
    int t = threadIdx.x;
    int v = (t < NBLK) ? bsum[t] : 0;
    s[t] = v;
    __syncthreads();
    #pragma unroll
    for (int o = 1; o < 128; o <<= 1) {
        int u = (t >= o) ? s[t - o] : 0;
        __syncthreads();
        s[t] += u;
        __syncthreads();
    }
    if (t < NBLK) bsum[t] = s[t] - v;   // exclusive block offset
    if (t == 127) off[NN] = s[127];     // grand total
}

__global__ __launch_bounds__(1024) void deg_block_scan(int* __restrict__ deg,
                                                       int* __restrict__ off,
                                                       const int* __restrict__ bsum)
{
    __shared__ int s[1024];
    int t = threadIdx.x;
    int i = blockIdx.x * 1024 + t;
    int v = (i < NN) ? deg[i] : 0;
    s[t] = v;
    __syncthreads();
    #pragma unroll
    for (int o = 1; o < 1024; o <<= 1) {
        int u = (t >= o) ? s[t - o] : 0;
        __syncthreads();
        s[t] += u;
        __syncthreads();
    }
    int excl = s[t] - v + bsum[blockIdx.x];
    if (i < NN) { off[i] = excl; deg[i] = excl; }
}

__global__ __launch_bounds__(256) void scatter_perm(const int* __restrict__ ei,
                                                    int* __restrict__ cur,
                                                    int2* __restrict__ perm2)
{
    int i = blockIdx.x * 256 + threadIdx.x;
    int stride = gridDim.x * 256;
    for (int e = i; e < NE; e += stride) {
        int s = ei[e];
        int d = ei[NE + e];
        int pos = atomicAdd(&cur[d], 1);
        perm2[pos] = make_int2(e, s);
    }
}

// ===========================================================================
// conv1 gather via MFMA: the edge-linear ea@We IS a 16-edge x 128-ch GEMM,
// and the matrix pipe broadcasts operands in HARDWARE (rounds 3-10 showed
// every software broadcast path costs >=150 cyc/edge: readlane 219us,
// SMEM 227, bpermute 413, VMEM-uniform 374, LDS-stage 584).
// One wave per node (persistent, grid-stride). Per 16-edge tile:
//   A[16x32] = edge attrs (K=16 real, 16-31 zero in BOTH A and B)
//   B[32x16ch] x 8 blocks = We in bf16 (resident VGPRs, one-time prep)
//   C init = bias; mfma_f32_16x16x32_bf16 -> C[row=edge, col=ch]
//   epilogue: x[src(row)][ch] + C, relu, validity-masked accumulate
// Lane mapping (m89-verified C layout): col=lane&15, row=(lane>>4)*4+reg.
// A: row=lane&15, k=(lane>>4)*8+j contiguous (m92/m97 ds_read_b128 pattern).
// Precision: ea,We bf16-RNE; fp32 accumulate (tolerance 0.03125 >> ~0.005).
// ===========================================================================
__global__ __launch_bounds__(256, 4) void conv1_gather(
    const float* __restrict__ x, const float* __restrict__ ea,
    const float* __restrict__ We, const float* __restrict__ be,
    const int* __restrict__ off, const int2* __restrict__ perm2,
    float* __restrict__ aggr)
{
    int t = threadIdx.x;
    int lane = t & 63;
    int col  = lane & 15;            // ch within block / A row (edge)
    int kg   = lane >> 4;            // k-group; kg>=2 holds k>=16 -> zero
    int khalf = (kg & 1) * 8;        // safe k base (0 or 8)
    unsigned zmask = (kg < 2) ? 0xFFFFFFFFu : 0u;
    int rbase = kg << 2;             // this lane's first C row

    // ---- one-time B fragments (8 ch-blocks) + bias ----
    ABu B[8];
    float biasv[8];
    #pragma unroll
    for (int b = 0; b < 8; b++) {
        int ch = (b << 4) + col;
        #pragma unroll
        for (int i = 0; i < 4; i++) {
            int k = khalf + i * 2;
            B[b].u[i] = pkbf16(We[k * 128 + ch], We[(k + 1) * 128 + ch]) & zmask;
        }
        biasv[b] = be[ch];
    }

    for (int n = blockIdx.x * 4 + (t >> 6); n < NN; n += gridDim.x * 4) {
        int j0 = off[n], j1 = off[n + 1];
        int cnt = j1 - j0;
        if (cnt <= 0) {
            if (lane < 16) {
                #pragma unroll
                for (int b = 0; b < 8; b++)
                    aggr[(size_t)n * 128 + (b << 4) + lane] = 0.f;
            }
            continue;
        }
        float acc[8] = {0.f, 0.f, 0.f, 0.f, 0.f, 0.f, 0.f, 0.f};

        for (int T = 0; T < cnt; T += 16) {
            // ---- A fragment: row=col's edge, k=khalf..+7 (clamped rows) ----
            int eA = perm2[j0 + min(T + col, cnt - 1)].x;
            const float* ap = ea + (size_t)(unsigned)eA * 16 + khalf;
            float4 a0 = *(const float4*)ap;
            float4 a1 = *(const float4*)(ap + 4);
            ABu A;
            A.u[0] = pkbf16(a0.x, a0.y) & zmask;
            A.u[1] = pkbf16(a0.z, a0.w) & zmask;
            A.u[2] = pkbf16(a1.x, a1.y) & zmask;
            A.u[3] = pkbf16(a1.z, a1.w) & zmask;

            // ---- src + validity for this lane's 4 C rows ----
            int s_[4]; bool v_[4];
            #pragma unroll
            for (int r = 0; r < 4; r++) {
                int row = T + rbase + r;
                s_[r] = perm2[j0 + min(row, cnt - 1)].y;
                v_[r] = row < cnt;
            }

            // ---- two halves of 4 blocks: x-gather then MFMA+epilogue ----
            #pragma unroll
            for (int h2 = 0; h2 < 2; h2++) {
                float xv[4][4];
                #pragma unroll
                for (int b = 0; b < 4; b++)
                    #pragma unroll
                    for (int r = 0; r < 4; r++)
                        xv[b][r] = x[(size_t)(unsigned)s_[r] * 128 +
                                     ((h2 * 4 + b) << 4) + col];
                #pragma unroll
                for (int b = 0; b < 4; b++) {
                    int bb = h2 * 4 + b;
                    f32x4 c = {biasv[bb], biasv[bb], biasv[bb], biasv[bb]};
                    c = __builtin_amdgcn_mfma_f32_16x16x32_bf16(A.v, B[bb].v, c, 0, 0, 0);
                    #pragma unroll
                    for (int r = 0; r < 4; r++) {
                        float u = fmaxf(xv[b][r] + c[r], 0.f);
                        acc[bb] += v_[r] ? u : 0.f;
                    }
                }
            }
        }
        // ---- sum over the 4 row-groups (lanes ^16, ^32) ----
        #pragma unroll
        for (int b = 0; b < 8; b++) {
            float v = acc[b];
            v += __shfl_xor(v, 16);
            v += __shfl_xor(v, 32);
            acc[b] = v;
        }
        if (lane < 16) {
            #pragma unroll
            for (int b = 0; b < 8; b++)
                aggr[(size_t)n * 128 + (b << 4) + lane] = acc[b];
        }
    }
}

// ===========================================================================
// conv_mu + conv_logstd fused via MFMA: same A (edge attrs); B blocks 0-3
// from We2 (mu), 4-7 from We3 (logstd) -> one MFMA pass computes both
// trees' messages. h row is 64 ch; trees read the same h (L1 hits).
// ===========================================================================
__global__ __launch_bounds__(256, 4) void conv23_gather(
    const float* __restrict__ h, const float* __restrict__ ea,
    const float* __restrict__ We2, const float* __restrict__ be2,
    const float* __restrict__ We3, const float* __restrict__ be3,
    const int* __restrict__ off, const int2* __restrict__ perm2,
    float* __restrict__ aggr2, float* __restrict__ aggr3)
{
    int t = threadIdx.x;
    int lane = t & 63;
    int col  = lane & 15;
    int kg   = lane >> 4;
    int khalf = (kg & 1) * 8;
    unsigned zmask = (kg < 2) ? 0xFFFFFFFFu : 0u;
    int rbase = kg << 2;

    ABu B[8];
    float biasv[8];
    #pragma unroll
    for (int b = 0; b < 8; b++) {
        int ch = ((b & 3) << 4) + col;
        const float* W = (b < 4) ? We2 : We3;
        #pragma unroll
        for (int i = 0; i < 4; i++) {
            int k = khalf + i * 2;
            B[b].u[i] = pkbf16(W[k * 64 + ch], W[(k + 1) * 64 + ch]) & zmask;
        }
        biasv[b] = (b < 4) ? be2[ch] : be3[ch];
    }

    for (int n = blockIdx.x * 4 + (t >> 6); n < NN; n += gridDim.x * 4) {
        int j0 = off[n], j1 = off[n + 1];
        int cnt = j1 - j0;
        if (cnt <= 0) {
            if (lane < 16) {
                #pragma unroll
                for (int b = 0; b < 4; b++) {
                    aggr2[(size_t)n * 64 + (b << 4) + lane] = 0.f;
                    aggr3[(size_t)n * 64 + (b << 4) + lane] = 0.f;
                }
            }
            continue;
        }
        float acc[8] = {0.f, 0.f, 0.f, 0.f, 0.f, 0.f, 0.f, 0.f};

        for (int T = 0; T < cnt; T += 16) {
            int eA = perm2[j0 + min(T + col, cnt - 1)].x;
            const float* ap = ea + (size_t)(unsigned)eA * 16 + khalf;
            float4 a0 = *(const float4*)ap;
            float4 a1 = *(const float4*)(ap + 4);
            ABu A;
            A.u[0] = pkbf16(a0.x, a0.y) & zmask;
            A.u[1] = pkbf16(a0.z, a0.w) & zmask;
            A.u[2] = pkbf16(a1.x, a1.y) & zmask;
            A.u[3] = pkbf16(a1.z, a1.w) & zmask;

            int s_[4]; bool v_[4];
            #pragma unroll
            for (int r = 0; r < 4; r++) {
                int row = T + rbase + r;
                s_[r] = perm2[j0 + min(row, cnt - 1)].y;
                v_[r] = row < cnt;
            }

            #pragma unroll
            for (int h2 = 0; h2 < 2; h2++) {
                float hv[4][4];
                #pragma unroll
                for (int b = 0; b < 4; b++)
                    #pragma unroll
                    for (int r = 0; r < 4; r++)
                        hv[b][r] = h[(size_t)(unsigned)s_[r] * 64 + (b << 4) + col];
                #pragma unroll
                for (int b = 0; b < 4; b++) {
                    int bb = h2 * 4 + b;
                    f32x4 c = {biasv[bb], biasv[bb], biasv[bb], biasv[bb]};
                    c = __builtin_amdgcn_mfma_f32_16x16x32_bf16(A.v, B[bb].v, c, 0, 0, 0);
                    #pragma unroll
                    for (int r = 0; r < 4; r++) {
                        float u = fmaxf(hv[b][r] + c[r], 0.f);
                        acc[bb] += v_[r] ? u : 0.f;
                    }
                }
            }
        }
        #pragma unroll
        for (int b = 0; b < 8; b++) {
            float v = acc[b];
            v += __shfl_xor(v, 16);
            v += __shfl_xor(v, 32);
            acc[b] = v;
        }
        if (lane < 16) {
            #pragma unroll
            for (int b = 0; b < 4; b++) {
                aggr2[(size_t)n * 64 + (b << 4) + lane] = acc[b];
                aggr3[(size_t)n * 64 + (b << 4) + lane] = acc[4 + b];
            }
        }
    }
}

// ===========================================================================
// Node MLP: out = epilogue( relu((xin+aggr) @ Wa + ba) @ Wb + bb )
// KIN -> 64 -> 64. 64 nodes per block, 256 threads, 4x4 register tiles.
// SLIM-LDS (R9 win): weights/biases read directly from global.
// mode: 0 = none, 1 = relu, 2 = clip(-10, 10)
// ===========================================================================
template <int KIN>
__global__ __launch_bounds__(256) void node_mlp(
    const float* __restrict__ xin, const float* __restrict__ aggr,
    const float* __restrict__ Wa, const float* __restrict__ ba,
    const float* __restrict__ Wb, const float* __restrict__ bb,
    float* __restrict__ out, int mode)
{
    constexpr int S0 = KIN + 4;
    constexpr int K4 = KIN / 4;
    __shared__ float sh[64 * S0];
    int t = threadIdx.x;

    int nb = blockIdx.x << 6;
    for (int i = t; i < 64 * K4; i += 256) {
        int n = i / K4, k4 = i % K4;
        int node = nb + n;
        float4 v = make_float4(0.f, 0.f, 0.f, 0.f);
        if (node < NN) {
            float4 a = ((const float4*)(xin  + (size_t)node * KIN))[k4];
            float4 b = ((const float4*)(aggr + (size_t)node * KIN))[k4];
            v = make_float4(a.x + b.x, a.y + b.y, a.z + b.z, a.w + b.w);
        }
        *(float4*)&sh[n * S0 + (k4 << 2)] = v;
    }
    __syncthreads();

    int tx = t & 15, ty = t >> 4;
    int c0 = tx << 2, n0 = ty << 2;

    float4 b1 = *(const float4*)&ba[c0];
    float acc[4][4];
    #pragma unroll
    for (int i = 0; i < 4; i++) { acc[i][0] = b1.x; acc[i][1] = b1.y; acc[i][2] = b1.z; acc[i][3] = b1.w; }
    for (int k4 = 0; k4 < K4; k4++) {
        int k = k4 << 2;
        float4 w0 = *(const float4*)&Wa[((k + 0) << 6) + c0];
        float4 w1 = *(const float4*)&Wa[((k + 1) << 6) + c0];
        float4 w2 = *(const float4*)&Wa[((k + 2) << 6) + c0];
        float4 w3 = *(const float4*)&Wa[((k + 3) << 6) + c0];
        #pragma unroll
        for (int i = 0; i < 4; i++) {
            float4 hv = *(const float4*)&sh[(n0 + i) * S0 + k];
            acc[i][0] = fmaf(hv.x, w0.x, acc[i][0]); acc[i][1] = fmaf(hv.x, w0.y, acc[i][1]);
            acc[i][2] = fmaf(hv.x, w0.z, acc[i][2]); acc[i][3] = fmaf(hv.x, w0.w, acc[i][3]);
            acc[i][0] = fmaf(hv.y, w1.x, acc[i][0]); acc[i][1] = fmaf(hv.y, w1.y, acc[i][1]);
            acc[i][2] = fmaf(hv.y, w1.z, acc[i][2]); acc[i][3] = fmaf(hv.y, w1.w, acc[i][3]);
            acc[i][0] = fmaf(hv.z, w2.x, acc[i][0]); acc[i][1] = fmaf(hv.z, w2.y, acc[i][1]);
            acc[i][2] = fmaf(hv.z, w2.z, acc[i][2]); acc[i][3] = fmaf(hv.z, w2.w, acc[i][3]);
            acc[i][0] = fmaf(hv.w, w3.x, acc[i][0]); acc[i][1] = fmaf(hv.w, w3.y, acc[i][1]);
            acc[i][2] = fmaf(hv.w, w3.z, acc[i][2]); acc[i][3] = fmaf(hv.w, w3.w, acc[i][3]);
        }
    }
    __syncthreads();
    #pragma unroll
    for (int i = 0; i < 4; i++) {
        float4 v = make_float4(fmaxf(acc[i][0], 0.f), fmaxf(acc[i][1], 0.f),
                               fmaxf(acc[i][2], 0.f), fmaxf(acc[i][3], 0.f));
        *(float4*)&sh[(n0 + i) * 68 + c0] = v;
    }
    __syncthreads();

    float4 b2 = *(const float4*)&bb[c0];
    float acc2[4][4];
    #pragma unroll
    for (int i = 0; i < 4; i++) { acc2[i][0] = b2.x; acc2[i][1] = b2.y; acc2[i][2] = b2.z; acc2[i][3] = b2.w; }
    for (int k4 = 0; k4 < 16; k4++) {
        int k = k4 << 2;
        float4 w0 = *(const float4*)&Wb[((k + 0) << 6) + c0];
        float4 w1 = *(const float4*)&Wb[((k + 1) << 6) + c0];
        float4 w2 = *(const float4*)&Wb[((k + 2) << 6) + c0];
        float4 w3 = *(const float4*)&Wb[((k + 3) << 6) + c0];
        #pragma unroll
        for (int i = 0; i < 4; i++) {
            float4 hv = *(const float4*)&sh[(n0 + i) * 68 + k];
            acc2[i][0] = fmaf(hv.x, w0.x, acc2[i][0]); acc2[i][1] = fmaf(hv.x, w0.y, acc2[i][1]);
            acc2[i][2] = fmaf(hv.x, w0.z, acc2[i][2]); acc2[i][3] = fmaf(hv.x, w0.w, acc2[i][3]);
            acc2[i][0] = fmaf(hv.y, w1.x, acc2[i][0]); acc2[i][1] = fmaf(hv.y, w1.y, acc2[i][1]);
            acc2[i][2] = fmaf(hv.y, w1.z, acc2[i][2]); acc2[i][3] = fmaf(hv.y, w1.w, acc2[i][3]);
            acc2[i][0] = fmaf(hv.z, w2.x, acc2[i][0]); acc2[i][1] = fmaf(hv.z, w2.y, acc2[i][1]);
            acc2[i][2] = fmaf(hv.z, w2.z, acc2[i][2]); acc2[i][3] = fmaf(hv.z, w2.w, acc2[i][3]);
            acc2[i][0] = fmaf(hv.w, w3.x, acc2[i][0]); acc2[i][1] = fmaf(hv.w, w3.y, acc2[i][1]);
            acc2[i][2] = fmaf(hv.w, w3.z, acc2[i][2]); acc2[i][3] = fmaf(hv.w, w3.w, acc2[i][3]);
        }
    }

    #pragma unroll
    for (int i = 0; i < 4; i++) {
        int node = nb + n0 + i;
        if (node >= NN) continue;
        float4 v = make_float4(acc2[i][0], acc2[i][1], acc2[i][2], acc2[i][3]);
        if (mode == 1) {
            v = make_float4(fmaxf(v.x, 0.f), fmaxf(v.y, 0.f), fmaxf(v.z, 0.f), fmaxf(v.w, 0.f));
        } else if (mode == 2) {
            v = make_float4(fminf(fmaxf(v.x, -10.f), 10.f), fminf(fmaxf(v.y, -10.f), 10.f),
                            fminf(fmaxf(v.z, -10.f), 10.f), fminf(fmaxf(v.w, -10.f), 10.f));
        }
        *(float4*)(out + (size_t)node * 64 + c0) = v;
    }
}

extern "C" void kernel_launch(void* const* d_in, const int* in_sizes, int n_in,
                              void* d_out, int out_size, void* d_ws, size_t ws_size,
                              hipStream_t stream)
{
    const float* x   = (const float*)d_in[0];
    const int*   ei  = (const int*)  d_in[1];
    const float* ea  = (const float*)d_in[2];
    const float* We1 = (const float*)d_in[3];
    const float* be1 = (const float*)d_in[4];
    const float* W1a = (const float*)d_in[5];
    const float* b1a = (const float*)d_in[6];
    const float* W1b = (const float*)d_in[7];
    const float* b1b = (const float*)d_in[8];
    const float* We2 = (const float*)d_in[9];
    const float* be2 = (const float*)d_in[10];
    const float* W2a = (const float*)d_in[11];
    const float* b2a = (const float*)d_in[12];
    const float* W2b = (const float*)d_in[13];
    const float* b2b = (const float*)d_in[14];
    const float* We3 = (const float*)d_in[15];
    const float* be3 = (const float*)d_in[16];
    const float* W3a = (const float*)d_in[17];
    const float* b3a = (const float*)d_in[18];
    const float* W3b = (const float*)d_in[19];
    const float* b3b = (const float*)d_in[20];

    float* out = (float*)d_out;
    float* ws = (float*)d_ws;
    // float scratch: aggr1 [12.8M] (later aliased by aggr2/aggr3), h [6.4M]
    float* aggr1 = ws;
    float* h     = ws + 12800000;
    float* aggr2 = ws;              // aliases aggr1 (dead after node_mlp<128>)
    float* aggr3 = ws + 6400000;
    // int scratch after 19.2M floats: off [NN+1], cur [NN], perm2 [2*NE]
    int* ibase = (int*)(ws + 19200000);
    int* off   = ibase;
    int* cur   = ibase + (NN + 1);
    int2* perm2 = (int2*)(ibase + (2 * NN + 2));
    // 98 block sums live in the (currently idle) aggr3 float region —
    // CSR build completes before any conv kernel touches aggr3.
    int* bsum  = (int*)(ws + 6400000);

    // ---- CSR build (shared by conv1 and conv23) ----
    hipMemsetAsync(cur, 0, (size_t)NN * sizeof(int), stream);
    hist_dst<<<2048, 256, 0, stream>>>(ei, cur);
    deg_block_sum<<<NBLK, 1024, 0, stream>>>(cur, bsum);
    scan_bsum<<<1, 128, 0, stream>>>(bsum, off);
    deg_block_scan<<<NBLK, 1024, 0, stream>>>(cur, off, bsum); // cur -> cursor
    scatter_perm<<<2048, 256, 0, stream>>>(ei, cur, perm2);

    // ---- layer 1 ----
    conv1_gather<<<1024, 256, 0, stream>>>(x, ea, We1, be1, off, perm2, aggr1);
    node_mlp<128><<<(NN + 63) / 64, 256, 0, stream>>>(x, aggr1, W1a, b1a, W1b, b1b, h, 1);

    // ---- layers 2+3 (fused edge pass) ----
    conv23_gather<<<1024, 256, 0, stream>>>(h, ea, We2, be2, We3, be3,
                                            off, perm2, aggr2, aggr3);
    node_mlp<64><<<(NN + 63) / 64, 256, 0, stream>>>(h, aggr2, W2a, b2a, W2b, b2b, out, 0);
    node_mlp<64><<<(NN + 63) / 64, 256, 0, stream>>>(h, aggr3, W3a, b3a, W3b, b3b,
                                                     out + (size_t)NN * 64, 2);
}